// Round 1
// baseline (1501.190 us; speedup 1.0000x reference)
//
#include <hip/hip_runtime.h>
#include <hip/hip_bf16.h>

#define DEV __device__ __forceinline__

typedef unsigned short u16;
typedef short short8 __attribute__((ext_vector_type(8)));
typedef float f32x4 __attribute__((ext_vector_type(4)));

constexpr int HID  = 1152;
constexpr int NSEQ = 4096;
constexpr int NB   = 8;
constexpr int MROWS = NB * NSEQ;      // 32768
constexpr int MLP  = 4608;
constexpr float EPSV  = 1e-6f;
constexpr float SCALE = 0.11785113019775793f; // 72^-0.5

// ---- workspace layout (bytes) ----
constexpr size_t O_WT1  = 0;
constexpr size_t SZ_WT1 = (size_t)MLP * HID * 2;        // 10,616,832
constexpr size_t O_WT2  = O_WT1 + SZ_WT1;
constexpr size_t SZ_WT2 = (size_t)HID * MLP * 2;
constexpr size_t O_H    = O_WT2 + SZ_WT2;
constexpr size_t SZ_H   = (size_t)MROWS * HID * 2;      // 75,497,472
constexpr size_t O_MODS = O_H + SZ_H;
constexpr size_t O_K    = O_MODS + (size_t)NB*6912*4;
constexpr size_t O_V    = O_K + (size_t)16*HID*4;
constexpr size_t O_U    = O_V + (size_t)16*HID*4;
constexpr size_t O_A1   = O_U + (size_t)16*HID*4;
constexpr size_t O_S0   = O_A1 + (size_t)16*HID*4;
constexpr size_t O_S1   = O_S0 + 64;
constexpr size_t O_P    = O_S1 + 64;
constexpr size_t O_ACT  = O_P + (size_t)NB*NSEQ*2*4;

DEV u16 f2bf(float f){
  __hip_bfloat16 h = __float2bfloat16(f);
  u16 u; __builtin_memcpy(&u, &h, 2); return u;
}

DEV float wsum(float v){
  #pragma unroll
  for (int o = 32; o; o >>= 1) v += __shfl_xor(v, o, 64);
  return v;
}

DEV void cp16(void* lds, const void* g){
  __builtin_amdgcn_global_load_lds(
      (__attribute__((address_space(1))) void*)g,
      (__attribute__((address_space(3))) void*)lds, 16, 0, 0);
}

// ---------------- transpose + cast fp32 (K,N) -> bf16 (N,K) ----------------
__global__ void tcast_k(const float* __restrict__ in, u16* __restrict__ out, int K, int N){
  __shared__ float tile[32][33];
  int n0 = blockIdx.x * 32, k0 = blockIdx.y * 32;
  int tx = threadIdx.x, ty = threadIdx.y;
  #pragma unroll
  for (int i = 0; i < 32; i += 8)
    tile[ty + i][tx] = in[(size_t)(k0 + ty + i) * N + (n0 + tx)];
  __syncthreads();
  #pragma unroll
  for (int i = 0; i < 32; i += 8)
    out[(size_t)(n0 + ty + i) * K + (k0 + tx)] = f2bf(tile[tx][ty + i]);
}

// ---------------- mods = silu(c) @ w_ada + b_ada ----------------
__global__ void mods_k(const float* __restrict__ cv, const float* __restrict__ w_ada,
                       const float* __restrict__ b_ada, float* __restrict__ modsb){
  int b = blockIdx.y;
  __shared__ float cs[HID];
  int tid = threadIdx.x;
  for (int i = tid; i < HID; i += 256){
    float t = cv[b*HID + i];
    cs[i] = t / (1.f + __expf(-t));
  }
  __syncthreads();
  int col = blockIdx.x * 256 + tid;
  float acc = b_ada[col];
  #pragma unroll 4
  for (int k = 0; k < HID; k++) acc += cs[k] * w_ada[(size_t)k*6912 + col];
  modsb[b*6912 + col] = acc;
}

// ---------------- kv = modulate(ln(x0), sh_msa, sc_msa) @ w1 + b1 ----------------
__global__ void kv_k(const float* __restrict__ x, const float* __restrict__ modsb,
                     const float* __restrict__ w1, const float* __restrict__ b1,
                     float* __restrict__ kbuf, float* __restrict__ vbuf){
  int bt = blockIdx.y; int b = bt >> 1, t = bt & 1;
  int tid = threadIdx.x;
  __shared__ float mx[HID];
  __shared__ float rbuf[8];
  __shared__ float s_mu, s_rs;
  const float* xr = x + ((size_t)b*NSEQ + t) * HID;
  float sx = 0.f, sxx = 0.f;
  for (int i = tid; i < HID; i += 256){ float v = xr[i]; sx += v; sxx += v*v; }
  sx = wsum(sx); sxx = wsum(sxx);
  int wave = tid >> 6, lane = tid & 63;
  if (lane == 0){ rbuf[wave] = sx; rbuf[4+wave] = sxx; }
  __syncthreads();
  if (tid == 0){
    float a = rbuf[0]+rbuf[1]+rbuf[2]+rbuf[3];
    float bb = rbuf[4]+rbuf[5]+rbuf[6]+rbuf[7];
    float mu = a * (1.f/HID);
    float var = bb * (1.f/HID) - mu*mu;
    s_mu = mu; s_rs = rsqrtf(var + EPSV);
  }
  __syncthreads();
  float mu = s_mu, rs = s_rs;
  const float* md = modsb + b*6912;
  for (int i = tid; i < HID; i += 256)
    mx[i] = (xr[i]-mu)*rs*(1.f + md[HID+i]) + md[i];
  __syncthreads();
  int col = blockIdx.x * 256 + tid;  // 0..2303
  float acc = b1[col];
  #pragma unroll 4
  for (int k = 0; k < HID; k++) acc += mx[k] * w1[(size_t)k*2304 + col];
  if (col < HID) kbuf[bt*HID + col] = acc;
  else           vbuf[bt*HID + col - HID] = acc;
}

// ---------------- u[b,m,j] = sum_i W2[j,i] k[b,m,i];  A1 = (1+sc_msa)*u ----------------
__global__ void u_k(const float* __restrict__ w2, const float* __restrict__ kbuf,
                    const float* __restrict__ modsb, float* __restrict__ ub,
                    float* __restrict__ A1b){
  int bm = blockIdx.x; int b = bm >> 1;
  int tid = threadIdx.x;
  __shared__ float ks[HID];
  for (int i = tid; i < HID; i += 256) ks[i] = kbuf[bm*HID + i];
  __syncthreads();
  const float* md = modsb + b*6912;
  for (int j = tid; j < HID; j += 256){
    const float* wr = w2 + (size_t)j*HID;
    float acc = 0.f;
    #pragma unroll 4
    for (int i = 0; i < HID; i++) acc += wr[i] * ks[i];
    ub[bm*HID + j] = acc;
    A1b[bm*HID + j] = (1.f + md[HID + j]) * acc;
  }
}

// ---------------- S1[bm]=sum A1; S0[bm]=sum sh_msa*u + sum b2*k ----------------
__global__ void sred_k(const float* __restrict__ ub, const float* __restrict__ A1b,
                       const float* __restrict__ modsb, const float* __restrict__ b2,
                       const float* __restrict__ kbuf, float* __restrict__ S0,
                       float* __restrict__ S1){
  int bm = blockIdx.x; int b = bm >> 1;
  int tid = threadIdx.x;
  float s0 = 0.f, s1 = 0.f;
  const float* md = modsb + b*6912;
  for (int i = tid; i < HID; i += 256){
    s1 += A1b[bm*HID + i];
    s0 += md[i]*ub[bm*HID + i] + b2[i]*kbuf[bm*HID + i];
  }
  s0 = wsum(s0); s1 = wsum(s1);
  __shared__ float rb[16];
  int wave = tid >> 6, lane = tid & 63;
  if (lane == 0){ rb[wave] = s0; rb[8+wave] = s1; }
  __syncthreads();
  if (tid == 0){
    S0[bm] = rb[0]+rb[1]+rb[2]+rb[3];
    S1[bm] = rb[8]+rb[9]+rb[10]+rb[11];
  }
}

// ---------------- p[b,n] = softmax over 2 keys (one wave per row) ----------------
__global__ void p_k(const float* __restrict__ x, const float* __restrict__ A1b,
                    const float* __restrict__ S0, const float* __restrict__ S1,
                    float2* __restrict__ pb){
  int tid = threadIdx.x, wave = tid >> 6, lane = tid & 63;
  int row0 = blockIdx.x * 4;
  int b = row0 >> 12;
  __shared__ float a1s[2*HID];
  for (int i = tid; i < 2*HID; i += 256) a1s[i] = A1b[b*2*HID + i];
  __syncthreads();
  int row = row0 + wave;
  const float* xr = x + (size_t)row * HID;
  float sx = 0.f, sxx = 0.f, d0 = 0.f, d1 = 0.f;
  #pragma unroll
  for (int i = 0; i < 9; i++){
    int cc = lane*2 + i*128;
    float2 v = *(const float2*)(xr + cc);
    sx += v.x + v.y; sxx += v.x*v.x + v.y*v.y;
    d0 += v.x*a1s[cc]       + v.y*a1s[cc+1];
    d1 += v.x*a1s[HID+cc]   + v.y*a1s[HID+cc+1];
  }
  sx = wsum(sx); sxx = wsum(sxx); d0 = wsum(d0); d1 = wsum(d1);
  if (lane == 0){
    float mu = sx * (1.f/HID);
    float var = sxx * (1.f/HID) - mu*mu;
    float rs = rsqrtf(var + EPSV);
    float sc0 = rs*(d0 - mu*S1[b*2+0]) + S0[b*2+0];
    float sc1 = rs*(d1 - mu*S1[b*2+1]) + S0[b*2+1];
    float z = (sc0 - sc1) * SCALE;
    float p0 = 1.f / (1.f + __expf(-z));
    pb[row] = make_float2(p0, 1.f - p0);
  }
}

// ---------------- H = bf16( modulate(ln(y2), sh_mlp, sc_mlp) ), one wave per row ----------------
__global__ void h_k(const float2* __restrict__ pb, const float* __restrict__ vbuf,
                    const float* __restrict__ modsb, u16* __restrict__ H){
  int tid = threadIdx.x, wave = tid >> 6, lane = tid & 63;
  int row0 = blockIdx.x * 4;
  int b = row0 >> 12;
  __shared__ float gs[HID], shs[HID], scs[HID];
  const float* md = modsb + b*6912;
  for (int i = tid; i < HID; i += 256){
    gs[i]  = 1.f + md[2*HID + i];
    shs[i] = md[3*HID + i];
    scs[i] = 1.f + md[4*HID + i];
  }
  __syncthreads();
  int row = row0 + wave;
  int n = row & (NSEQ-1);
  const float2* pbb = pb + ((size_t)b << 12);
  const float* vb0 = vbuf + b*2*HID;
  float yv[18];
  float sx = 0.f, sxx = 0.f;
  #pragma unroll
  for (int i = 0; i < 9; i++){
    int cc = lane*2 + i*128;
    int f = n*HID + cc;
    int r0 = f & (NSEQ-1), ci0 = f >> 12;
    int f1 = f + 1;
    int r1 = f1 & (NSEQ-1), ci1 = f1 >> 12;
    float2 pv0 = pbb[r0];
    float2 pv1 = pbb[r1];
    float y0 = gs[cc]   * (pv0.x*vb0[ci0] + pv0.y*vb0[HID+ci0]);
    float y1 = gs[cc+1] * (pv1.x*vb0[ci1] + pv1.y*vb0[HID+ci1]);
    yv[2*i] = y0; yv[2*i+1] = y1;
    sx += y0 + y1; sxx += y0*y0 + y1*y1;
  }
  sx = wsum(sx); sxx = wsum(sxx);
  float mu = sx * (1.f/HID);
  float var = sxx * (1.f/HID) - mu*mu;
  float rs = rsqrtf(var + EPSV);
  u16* Hr = H + (size_t)row * HID;
  #pragma unroll
  for (int i = 0; i < 9; i++){
    int cc = lane*2 + i*128;
    ushort2 st;
    st.x = f2bf((yv[2*i]   - mu)*rs*scs[cc]   + shs[cc]);
    st.y = f2bf((yv[2*i+1] - mu)*rs*scs[cc+1] + shs[cc+1]);
    *(ushort2*)(Hr + cc) = st;
  }
}

// ---------------- 128x128 bf16 MFMA GEMM, A:(rows,K) row-major, Bt:(Ntot,K) row-major ----------------
// EPI 0: out = bf16(gelu_tanh(acc + bias[col])) -> outB (row-local)
// EPI 1: out = y2 + g_mlp*(acc + bias[col])     -> outF (global rows via rowOffset)
template<int EPI>
__global__ __launch_bounds__(256, 2) void gemm_k(
    const u16* __restrict__ A, const u16* __restrict__ Bt,
    int K, int Ntot,
    const float* __restrict__ bias,
    u16* __restrict__ outB, float* __restrict__ outF,
    const float2* __restrict__ p, const float* __restrict__ vbuf,
    const float* __restrict__ modsb, int rowOffset){
  __align__(16) __shared__ u16 As[128*64];
  __align__(16) __shared__ u16 Bs[128*64];
  int tid = threadIdx.x;
  int wave = tid >> 6, lane = tid & 63;

  // XCD-chunk swizzle (grid total divisible by 8)
  int nT = gridDim.x;
  int d = blockIdx.y * nT + blockIdx.x;
  int q = (nT * gridDim.y) >> 3;
  int w = (d & 7) * q + (d >> 3);
  int bm = w / nT, bn = w - bm * nT;

  const u16* Ab = A + (size_t)bm * 128 * K;
  const u16* Bb = Bt + (size_t)bn * 128 * K;

  f32x4 acc[4][4] = {};

  int warpM = wave >> 1, warpN = wave & 1;
  int rA0 = warpM*64 + (lane & 15);
  int rB0 = warpN*64 + (lane & 15);
  int kk  = (lane >> 4) * 8;

  for (int kt = 0; kt < K; kt += 64){
    __syncthreads();
    #pragma unroll
    for (int i = 0; i < 4; i++){
      int e = i*256 + tid;
      int r = e >> 3, kc = e & 7;
      cp16(&As[e*8], Ab + (size_t)r*K + kt + kc*8);
    }
    #pragma unroll
    for (int i = 0; i < 4; i++){
      int e = i*256 + tid;
      int r = e >> 3, kc = e & 7;
      cp16(&Bs[e*8], Bb + (size_t)r*K + kt + kc*8);
    }
    __syncthreads();
    #pragma unroll
    for (int ks = 0; ks < 2; ks++){
      short8 av[4], bv[4];
      #pragma unroll
      for (int f = 0; f < 4; f++){
        av[f] = *(const short8*)&As[(rA0 + f*16)*64 + ks*32 + kk];
        bv[f] = *(const short8*)&Bs[(rB0 + f*16)*64 + ks*32 + kk];
      }
      #pragma unroll
      for (int fm = 0; fm < 4; fm++)
        #pragma unroll
        for (int fn = 0; fn < 4; fn++)
          acc[fm][fn] = __builtin_amdgcn_mfma_f32_16x16x32_bf16(av[fm], bv[fn], acc[fm][fn], 0, 0, 0);
    }
  }

  int colBase = bn*128 + warpN*64;
  int rowB    = bm*128 + warpM*64 + (lane >> 4)*4;

  if constexpr (EPI == 0){
    #pragma unroll
    for (int fn = 0; fn < 4; fn++){
      int col = colBase + fn*16 + (lane & 15);
      float bs = bias[col];
      #pragma unroll
      for (int fm = 0; fm < 4; fm++){
        int row0 = rowB + fm*16;
        #pragma unroll
        for (int r = 0; r < 4; r++){
          float xv = acc[fm][fn][r] + bs;
          float t = xv * (1.f + 0.044715f * xv * xv);
          float g = xv / (1.f + __expf(-1.5957691216057308f * t));
          outB[(size_t)(row0 + r)*Ntot + col] = f2bf(g);
        }
      }
    }
  } else {
    int bIdx = (rowOffset + bm*128) >> 12;   // 128-row tiles never straddle batches
    const float* md = modsb + bIdx*6912;
    const float2* pbb = p + ((size_t)bIdx << 12);
    const float* vb0 = vbuf + bIdx*2*HID;
    #pragma unroll
    for (int fn = 0; fn < 4; fn++){
      int col = colBase + fn*16 + (lane & 15);
      float bs = bias[col];
      float gmsa = 1.f + md[2*HID + col];
      float gmlp = md[5*HID + col];
      #pragma unroll
      for (int fm = 0; fm < 4; fm++){
        int row0 = rowB + fm*16;
        #pragma unroll
        for (int r = 0; r < 4; r++){
          int grow = rowOffset + row0 + r;
          int n = grow & (NSEQ-1);
          int f = n*HID + col;
          int rr = f & (NSEQ-1), ci = f >> 12;
          float2 pv = pbb[rr];
          float y2 = gmsa * (pv.x*vb0[ci] + pv.y*vb0[HID + ci]);
          outF[(size_t)grow*HID + col] = y2 + gmlp * (acc[fm][fn][r] + bs);
        }
      }
    }
  }
}

extern "C" void kernel_launch(void* const* d_in, const int* in_sizes, int n_in,
                              void* d_out, int out_size, void* d_ws, size_t ws_size,
                              hipStream_t stream){
  const float* x     = (const float*)d_in[0];
  const float* cvec  = (const float*)d_in[1];
  const float* w_ada = (const float*)d_in[2];
  const float* b_ada = (const float*)d_in[3];
  const float* w1    = (const float*)d_in[4];
  const float* b1    = (const float*)d_in[5];
  const float* w2    = (const float*)d_in[6];
  const float* b2    = (const float*)d_in[7];
  const float* w_fc1 = (const float*)d_in[8];
  const float* b_fc1 = (const float*)d_in[9];
  const float* w_fc2 = (const float*)d_in[10];
  const float* b_fc2 = (const float*)d_in[11];
  float* out = (float*)d_out;
  char* ws = (char*)d_ws;

  u16*   Wt1   = (u16*)  (ws + O_WT1);
  u16*   Wt2   = (u16*)  (ws + O_WT2);
  u16*   Hb    = (u16*)  (ws + O_H);
  float* modsb = (float*)(ws + O_MODS);
  float* kb    = (float*)(ws + O_K);
  float* vb    = (float*)(ws + O_V);
  float* ub    = (float*)(ws + O_U);
  float* A1b   = (float*)(ws + O_A1);
  float* S0b   = (float*)(ws + O_S0);
  float* S1b   = (float*)(ws + O_S1);
  float2* pb   = (float2*)(ws + O_P);
  u16*   actb  = (u16*)  (ws + O_ACT);

  tcast_k<<<dim3(MLP/32, HID/32), dim3(32,8), 0, stream>>>(w_fc1, Wt1, HID, MLP);
  tcast_k<<<dim3(HID/32, MLP/32), dim3(32,8), 0, stream>>>(w_fc2, Wt2, MLP, HID);
  mods_k<<<dim3(27, NB), 256, 0, stream>>>(cvec, w_ada, b_ada, modsb);
  kv_k<<<dim3(9, 16), 256, 0, stream>>>(x, modsb, w1, b1, kb, vb);
  u_k<<<16, 256, 0, stream>>>(w2, kb, modsb, ub, A1b);
  sred_k<<<16, 256, 0, stream>>>(ub, A1b, modsb, b2, kb, S0b, S1b);
  p_k<<<MROWS/4, 256, 0, stream>>>(x, A1b, S0b, S1b, pb);
  h_k<<<MROWS/4, 256, 0, stream>>>(pb, vb, modsb, Hb);

  size_t actFull = (size_t)MROWS * MLP * 2;
  int nch = 1;
  while (nch < 8 && O_ACT + actFull/nch > ws_size) nch <<= 1;
  int rowsPer = MROWS / nch;

  for (int chn = 0; chn < nch; chn++){
    int r0 = chn * rowsPer;
    gemm_k<0><<<dim3(MLP/128, rowsPer/128), 256, 0, stream>>>(
        Hb + (size_t)r0*HID, Wt1, HID, MLP, b_fc1,
        actb, nullptr, nullptr, nullptr, nullptr, 0);
    gemm_k<1><<<dim3(HID/128, rowsPer/128), 256, 0, stream>>>(
        actb, Wt2, MLP, HID, b_fc2,
        nullptr, out, pb, vb, modsb, r0);
  }
  (void)in_sizes; (void)n_in; (void)out_size;
}

// Round 2
// 1425.865 us; speedup vs baseline: 1.0528x; 1.0528x over previous
//
#include <hip/hip_runtime.h>
#include <hip/hip_bf16.h>

#define DEV __device__ __forceinline__

typedef unsigned short u16;
typedef short short8 __attribute__((ext_vector_type(8)));
typedef float f32x4 __attribute__((ext_vector_type(4)));

constexpr int HID  = 1152;
constexpr int NSEQ = 4096;
constexpr int NB   = 8;
constexpr int MROWS = NB * NSEQ;      // 32768
constexpr int MLP  = 4608;
constexpr int NPAD2 = 1280;           // GEMM2 B rows padded to 5*256
constexpr float EPSV  = 1e-6f;
constexpr float SCALE = 0.11785113019775793f; // 72^-0.5

// ---- workspace layout (bytes) ----
constexpr size_t O_WT1  = 0;
constexpr size_t SZ_WT1 = (size_t)MLP * HID * 2;
constexpr size_t O_WT2  = O_WT1 + SZ_WT1;
constexpr size_t SZ_WT2 = (size_t)NPAD2 * MLP * 2;
constexpr size_t O_H    = O_WT2 + SZ_WT2;
constexpr size_t SZ_H   = (size_t)MROWS * HID * 2;
constexpr size_t O_MODS = O_H + SZ_H;
constexpr size_t O_K    = O_MODS + (size_t)NB*6912*4;
constexpr size_t O_V    = O_K + (size_t)16*HID*4;
constexpr size_t O_U    = O_V + (size_t)16*HID*4;
constexpr size_t O_A1   = O_U + (size_t)16*HID*4;
constexpr size_t O_S0   = O_A1 + (size_t)16*HID*4;
constexpr size_t O_S1   = O_S0 + 64;
constexpr size_t O_P    = O_S1 + 64;
constexpr size_t O_ACT  = O_P + (size_t)NB*NSEQ*2*4;

#define BARR  asm volatile("s_barrier" ::: "memory")
#define VMW0  asm volatile("s_waitcnt vmcnt(0)" ::: "memory")
#define VMW4  asm volatile("s_waitcnt vmcnt(4)" ::: "memory")
#define VMW8  asm volatile("s_waitcnt vmcnt(8)" ::: "memory")
#define SP1   __builtin_amdgcn_s_setprio(1)
#define SP0   __builtin_amdgcn_s_setprio(0)

DEV u16 f2bf(float f){
  __hip_bfloat16 h = __float2bfloat16(f);
  u16 u; __builtin_memcpy(&u, &h, 2); return u;
}

DEV float wsum(float v){
  #pragma unroll
  for (int o = 32; o; o >>= 1) v += __shfl_xor(v, o, 64);
  return v;
}

DEV void cp16(void* lds, const void* g){
  __builtin_amdgcn_global_load_lds(
      (__attribute__((address_space(1))) void*)g,
      (__attribute__((address_space(3))) void*)lds, 16, 0, 0);
}

// ---------------- transpose + cast fp32 (K,N) -> bf16 (N,K) ----------------
__global__ void tcast_k(const float* __restrict__ in, u16* __restrict__ out, int K, int N){
  __shared__ float tile[32][33];
  int n0 = blockIdx.x * 32, k0 = blockIdx.y * 32;
  int tx = threadIdx.x, ty = threadIdx.y;
  #pragma unroll
  for (int i = 0; i < 32; i += 8)
    tile[ty + i][tx] = in[(size_t)(k0 + ty + i) * N + (n0 + tx)];
  __syncthreads();
  #pragma unroll
  for (int i = 0; i < 32; i += 8)
    out[(size_t)(n0 + ty + i) * K + (k0 + tx)] = f2bf(tile[tx][ty + i]);
}

// ---------------- mods = silu(c) @ w_ada + b_ada ----------------
__global__ void mods_k(const float* __restrict__ cv, const float* __restrict__ w_ada,
                       const float* __restrict__ b_ada, float* __restrict__ modsb){
  int b = blockIdx.y;
  __shared__ float cs[HID];
  int tid = threadIdx.x;
  for (int i = tid; i < HID; i += 256){
    float t = cv[b*HID + i];
    cs[i] = t / (1.f + __expf(-t));
  }
  __syncthreads();
  int col = blockIdx.x * 256 + tid;
  float acc = b_ada[col];
  #pragma unroll 4
  for (int k = 0; k < HID; k++) acc += cs[k] * w_ada[(size_t)k*6912 + col];
  modsb[b*6912 + col] = acc;
}

// ---------------- kv = modulate(ln(x0)) @ w1 + b1 ----------------
__global__ void kv_k(const float* __restrict__ x, const float* __restrict__ modsb,
                     const float* __restrict__ w1, const float* __restrict__ b1,
                     float* __restrict__ kbuf, float* __restrict__ vbuf){
  int bt = blockIdx.y; int b = bt >> 1, t = bt & 1;
  int tid = threadIdx.x;
  __shared__ float mx[HID];
  __shared__ float rbuf[8];
  __shared__ float s_mu, s_rs;
  const float* xr = x + ((size_t)b*NSEQ + t) * HID;
  float sx = 0.f, sxx = 0.f;
  for (int i = tid; i < HID; i += 256){ float v = xr[i]; sx += v; sxx += v*v; }
  sx = wsum(sx); sxx = wsum(sxx);
  int wave = tid >> 6, lane = tid & 63;
  if (lane == 0){ rbuf[wave] = sx; rbuf[4+wave] = sxx; }
  __syncthreads();
  if (tid == 0){
    float a = rbuf[0]+rbuf[1]+rbuf[2]+rbuf[3];
    float bb = rbuf[4]+rbuf[5]+rbuf[6]+rbuf[7];
    float mu = a * (1.f/HID);
    float var = bb * (1.f/HID) - mu*mu;
    s_mu = mu; s_rs = rsqrtf(var + EPSV);
  }
  __syncthreads();
  float mu = s_mu, rs = s_rs;
  const float* md = modsb + b*6912;
  for (int i = tid; i < HID; i += 256)
    mx[i] = (xr[i]-mu)*rs*(1.f + md[HID+i]) + md[i];
  __syncthreads();
  int col = blockIdx.x * 256 + tid;
  float acc = b1[col];
  #pragma unroll 4
  for (int k = 0; k < HID; k++) acc += mx[k] * w1[(size_t)k*2304 + col];
  if (col < HID) kbuf[bt*HID + col] = acc;
  else           vbuf[bt*HID + col - HID] = acc;
}

// ---------------- u = W2 k ; A1 = (1+sc_msa)*u ----------------
__global__ void u_k(const float* __restrict__ w2, const float* __restrict__ kbuf,
                    const float* __restrict__ modsb, float* __restrict__ ub,
                    float* __restrict__ A1b){
  int bm = blockIdx.x; int b = bm >> 1;
  int tid = threadIdx.x;
  __shared__ float ks[HID];
  for (int i = tid; i < HID; i += 256) ks[i] = kbuf[bm*HID + i];
  __syncthreads();
  const float* md = modsb + b*6912;
  for (int j = tid; j < HID; j += 256){
    const float* wr = w2 + (size_t)j*HID;
    float acc = 0.f;
    #pragma unroll 4
    for (int i = 0; i < HID; i++) acc += wr[i] * ks[i];
    ub[bm*HID + j] = acc;
    A1b[bm*HID + j] = (1.f + md[HID + j]) * acc;
  }
}

// ---------------- S1 = sum A1; S0 = sum sh_msa*u + sum b2*k ----------------
__global__ void sred_k(const float* __restrict__ ub, const float* __restrict__ A1b,
                       const float* __restrict__ modsb, const float* __restrict__ b2,
                       const float* __restrict__ kbuf, float* __restrict__ S0,
                       float* __restrict__ S1){
  int bm = blockIdx.x; int b = bm >> 1;
  int tid = threadIdx.x;
  float s0 = 0.f, s1 = 0.f;
  const float* md = modsb + b*6912;
  for (int i = tid; i < HID; i += 256){
    s1 += A1b[bm*HID + i];
    s0 += md[i]*ub[bm*HID + i] + b2[i]*kbuf[bm*HID + i];
  }
  s0 = wsum(s0); s1 = wsum(s1);
  __shared__ float rb[16];
  int wave = tid >> 6, lane = tid & 63;
  if (lane == 0){ rb[wave] = s0; rb[8+wave] = s1; }
  __syncthreads();
  if (tid == 0){
    S0[bm] = rb[0]+rb[1]+rb[2]+rb[3];
    S1[bm] = rb[8]+rb[9]+rb[10]+rb[11];
  }
}

// ---------------- p = softmax over 2 keys ----------------
__global__ void p_k(const float* __restrict__ x, const float* __restrict__ A1b,
                    const float* __restrict__ S0, const float* __restrict__ S1,
                    float2* __restrict__ pb){
  int tid = threadIdx.x, wave = tid >> 6, lane = tid & 63;
  int row0 = blockIdx.x * 4;
  int b = row0 >> 12;
  __shared__ float a1s[2*HID];
  for (int i = tid; i < 2*HID; i += 256) a1s[i] = A1b[b*2*HID + i];
  __syncthreads();
  int row = row0 + wave;
  const float* xr = x + (size_t)row * HID;
  float sx = 0.f, sxx = 0.f, d0 = 0.f, d1 = 0.f;
  #pragma unroll
  for (int i = 0; i < 9; i++){
    int cc = lane*2 + i*128;
    float2 v = *(const float2*)(xr + cc);
    sx += v.x + v.y; sxx += v.x*v.x + v.y*v.y;
    d0 += v.x*a1s[cc]       + v.y*a1s[cc+1];
    d1 += v.x*a1s[HID+cc]   + v.y*a1s[HID+cc+1];
  }
  sx = wsum(sx); sxx = wsum(sxx); d0 = wsum(d0); d1 = wsum(d1);
  if (lane == 0){
    float mu = sx * (1.f/HID);
    float var = sxx * (1.f/HID) - mu*mu;
    float rs = rsqrtf(var + EPSV);
    float sc0 = rs*(d0 - mu*S1[b*2+0]) + S0[b*2+0];
    float sc1 = rs*(d1 - mu*S1[b*2+1]) + S0[b*2+1];
    float z = (sc0 - sc1) * SCALE;
    float p0 = 1.f / (1.f + __expf(-z));
    pb[row] = make_float2(p0, 1.f - p0);
  }
}

// ---------------- H = bf16( modulate(ln(y2), sh_mlp, sc_mlp) ) ----------------
__global__ void h_k(const float2* __restrict__ pb, const float* __restrict__ vbuf,
                    const float* __restrict__ modsb, u16* __restrict__ H){
  int tid = threadIdx.x, wave = tid >> 6, lane = tid & 63;
  int row0 = blockIdx.x * 4;
  int b = row0 >> 12;
  __shared__ float gs[HID], shs[HID], scs[HID];
  const float* md = modsb + b*6912;
  for (int i = tid; i < HID; i += 256){
    gs[i]  = 1.f + md[2*HID + i];
    shs[i] = md[3*HID + i];
    scs[i] = 1.f + md[4*HID + i];
  }
  __syncthreads();
  int row = row0 + wave;
  int n = row & (NSEQ-1);
  const float2* pbb = pb + ((size_t)b << 12);
  const float* vb0 = vbuf + b*2*HID;
  float yv[18];
  float sx = 0.f, sxx = 0.f;
  #pragma unroll
  for (int i = 0; i < 9; i++){
    int cc = lane*2 + i*128;
    int f = n*HID + cc;
    int r0 = f & (NSEQ-1), ci0 = f >> 12;
    int f1 = f + 1;
    int r1 = f1 & (NSEQ-1), ci1 = f1 >> 12;
    float2 pv0 = pbb[r0];
    float2 pv1 = pbb[r1];
    float y0 = gs[cc]   * (pv0.x*vb0[ci0] + pv0.y*vb0[HID+ci0]);
    float y1 = gs[cc+1] * (pv1.x*vb0[ci1] + pv1.y*vb0[HID+ci1]);
    yv[2*i] = y0; yv[2*i+1] = y1;
    sx += y0 + y1; sxx += y0*y0 + y1*y1;
  }
  sx = wsum(sx); sxx = wsum(sxx);
  float mu = sx * (1.f/HID);
  float var = sxx * (1.f/HID) - mu*mu;
  float rs = rsqrtf(var + EPSV);
  u16* Hr = H + (size_t)row * HID;
  #pragma unroll
  for (int i = 0; i < 9; i++){
    int cc = lane*2 + i*128;
    ushort2 st;
    st.x = f2bf((yv[2*i]   - mu)*rs*scs[cc]   + shs[cc]);
    st.y = f2bf((yv[2*i+1] - mu)*rs*scs[cc+1] + shs[cc+1]);
    *(ushort2*)(Hr + cc) = st;
  }
}

// =========== 256x256 8-phase bf16 MFMA GEMM (T2+T3+T4+T5), BK=64 ===========
// A:(rows,K) row-major bf16; Bt:(NtotB,K) row-major bf16. 512 thr = 8 waves (2Mx4N).
// LDS: 2 dbuf x (A 256x64 + B 256x64) bf16 = 128 KiB, XOR-swizzled (r&7)<<4.
// EPI 0: outB = bf16(gelu_tanh(acc+bias)) stride MLP (rows chunk-local)
// EPI 1: outF = y2 + g_mlp*(acc+bias), cols masked < HID
template<int EPI>
__global__ __launch_bounds__(512, 2) void gemm8_k(
    const u16* __restrict__ A, const u16* __restrict__ Bt,
    int K, int nTn,
    const float* __restrict__ bias,
    u16* __restrict__ outB, float* __restrict__ outF,
    const float2* __restrict__ p, const float* __restrict__ vbuf,
    const float* __restrict__ modsb, int rowOffset)
{
  __shared__ u16 lds[2][2][256*64];
  const int tid = threadIdx.x;
  const int wave = tid >> 6, lane = tid & 63;
  const int wm = wave >> 2, wn = wave & 3;

  // bijective XCD swizzle (nwg % 8 == 0 guaranteed by launch config)
  int nwg = gridDim.x;
  int bid = blockIdx.x;
  int q = nwg >> 3;
  int w = (bid & 7) * q + (bid >> 3);
  int bm = w / nTn, bn = w - bm * nTn;

  const u16* Ab = A + (size_t)bm * 256 * K;
  const u16* Bb = Bt + (size_t)bn * 256 * K;

  f32x4 acc[8][4] = {};

  // issue one half-tile (128 rows x 64 cols) via 2x global_load_lds/thread.
  // LDS dest linear; global source pre-swizzled: k-slot = (lane&7)^(r&7).
  auto stage = [&](int buf, int ab, int half, int t){
    const u16* src = ab ? Bb : Ab;
    char* ldsb = (char*)&lds[buf][ab][0] + half*16384 + wave*2048 + lane*16;
    int rbase = half*128 + wave*16 + (lane>>3);
    int kof = t*64 + (((lane&7) ^ (lane>>3)) << 3);
    cp16(ldsb,        src + (size_t)rbase*K + kof);
    cp16(ldsb + 1024, src + (size_t)(rbase+8)*K + kof);
  };
  // ds-read A frags (4 m-frags x 2 k-slices), swizzled col
  auto ldA = [&](short8 (&v)[4][2], int buf, int mh){
    const char* base = (const char*)&lds[buf][0][0];
    int colb = (((lane>>4)<<4)) ^ ((lane&7)<<4);
    #pragma unroll
    for (int f = 0; f < 4; f++){
      const char* rp = base + (wm*128 + mh*64 + f*16 + (lane&15))*128;
      v[f][0] = *(const short8*)(rp + colb);
      v[f][1] = *(const short8*)(rp + (colb ^ 64));
    }
  };
  auto ldB = [&](short8 (&v)[2][2], int buf, int nh){
    const char* base = (const char*)&lds[buf][1][0];
    int colb = (((lane>>4)<<4)) ^ ((lane&7)<<4);
    #pragma unroll
    for (int f = 0; f < 2; f++){
      const char* rp = base + (wn*64 + nh*32 + f*16 + (lane&15))*128;
      v[f][0] = *(const short8*)(rp + colb);
      v[f][1] = *(const short8*)(rp + (colb ^ 64));
    }
  };
  auto mm = [&](short8 (&a)[4][2], short8 (&b)[2][2], int mh, int nh){
    #pragma unroll
    for (int ks = 0; ks < 2; ks++)
      #pragma unroll
      for (int f = 0; f < 4; f++)
        #pragma unroll
        for (int g = 0; g < 2; g++)
          acc[mh*4+f][nh*2+g] = __builtin_amdgcn_mfma_f32_16x16x32_bf16(
              a[f][ks], b[g][ks], acc[mh*4+f][nh*2+g], 0, 0, 0);
  };

  short8 av[4][2], av2[4][2], bv[2][2], bv2[2][2];

  // prologue: tile0 fully + tile1 fully; keep tile1's 8 loads outstanding
  stage(0,0,0,0); stage(0,0,1,0); stage(0,1,0,0); stage(0,1,1,0);
  stage(1,1,0,1); stage(1,1,1,1); stage(1,0,0,1); stage(1,0,1,1);
  VMW8; BARR;

  const int NIT = K >> 7;   // K/128: 2 k-tiles per iteration
  for (int it = 0; it < NIT; ++it){
    const int t2 = 2*it + 2, t3 = 2*it + 3;
    const bool fin = (it == NIT-1);
    // ph1: QA of tile 2i (buf0)
    ldA(av, 0, 0); ldB(bv, 0, 0);
    BARR; SP1; mm(av, bv, 0, 0); SP0; BARR;
    // ph2: QB
    ldB(bv2, 0, 1);
    BARR; SP1; mm(av, bv2, 0, 1); SP0; BARR;
    // ph3: QC; stage B(t2) h0 -> Bs[0] (B reads of buf0 done at ph2)
    ldA(av2, 0, 1);
    if (!fin) stage(0,1,0,t2);
    BARR; SP1; mm(av2, bv, 1, 0); SP0; BARR;
    // ph4: QD; stage B(t2) h1; counted wait -> tile 2i+1 landed
    if (!fin){ stage(0,1,1,t2); VMW4; } else { VMW0; }
    BARR; SP1; mm(av2, bv2, 1, 1); SP0; BARR;
    // ph5: QA of tile 2i+1 (buf1); stage A(t2) h0+h1 (A reads of buf0 done ph3)
    ldA(av, 1, 0); ldB(bv, 1, 0);
    if (!fin){ stage(0,0,0,t2); stage(0,0,1,t2); }
    BARR; SP1; mm(av, bv, 0, 0); SP0; BARR;
    // ph6: QB
    ldB(bv2, 1, 1);
    BARR; SP1; mm(av, bv2, 0, 1); SP0; BARR;
    // ph7: QC; stage B(t3) h0 (B reads of buf1 done ph6)
    ldA(av2, 1, 1);
    if (!fin) stage(1,1,0,t3);
    BARR; SP1; mm(av2, bv, 1, 0); SP0; BARR;
    // ph8: QD; stage B(t3) h1 + A(t3) h0+h1 (A reads of buf1 done ph7); wait -> tile 2i+2 landed
    if (!fin){ stage(1,1,1,t3); stage(1,0,0,t3); stage(1,0,1,t3); VMW8; }
    BARR; SP1; mm(av2, bv2, 1, 1); SP0; BARR;
  }

  // epilogue: C/D layout col=lane&15, row=(lane>>4)*4+r
  int colBase = bn*256 + wn*64;
  int rowB = bm*256 + wm*128 + ((lane>>4)<<2);
  if constexpr (EPI == 0){
    #pragma unroll
    for (int n = 0; n < 4; n++){
      int col = colBase + n*16 + (lane&15);
      float bs = bias[col];
      #pragma unroll
      for (int m = 0; m < 8; m++){
        #pragma unroll
        for (int r = 0; r < 4; r++){
          float xv = acc[m][n][r] + bs;
          float t = xv * (1.f + 0.044715f * xv * xv);
          float g = xv / (1.f + __expf(-1.5957691216057308f * t));
          outB[(size_t)(rowB + m*16 + r)*MLP + col] = f2bf(g);
        }
      }
    }
  } else {
    int bIdx = (rowOffset + bm*256) >> 12;   // 256-row tiles never straddle batches
    const float* md = modsb + bIdx*6912;
    const float2* pbb = p + ((size_t)bIdx << 12);
    const float* vb0 = vbuf + bIdx*2*HID;
    #pragma unroll
    for (int n = 0; n < 4; n++){
      int col = colBase + n*16 + (lane&15);
      if (col < HID){
        float bs = bias[col];
        float gmsa = 1.f + md[2*HID + col];
        float gmlp = md[5*HID + col];
        #pragma unroll
        for (int m = 0; m < 8; m++){
          #pragma unroll
          for (int r = 0; r < 4; r++){
            int grow = rowOffset + rowB + m*16 + r;
            int nn = grow & (NSEQ-1);
            int f = nn*HID + col;
            int rr = f & (NSEQ-1), ci = f >> 12;
            float2 pv = pbb[rr];
            float y2 = gmsa * (pv.x*vb0[ci] + pv.y*vb0[HID + ci]);
            outF[(size_t)grow*HID + col] = y2 + gmlp * (acc[m][n][r] + bs);
          }
        }
      }
    }
  }
}

extern "C" void kernel_launch(void* const* d_in, const int* in_sizes, int n_in,
                              void* d_out, int out_size, void* d_ws, size_t ws_size,
                              hipStream_t stream){
  const float* x     = (const float*)d_in[0];
  const float* cvec  = (const float*)d_in[1];
  const float* w_ada = (const float*)d_in[2];
  const float* b_ada = (const float*)d_in[3];
  const float* w1    = (const float*)d_in[4];
  const float* b1    = (const float*)d_in[5];
  const float* w2    = (const float*)d_in[6];
  const float* b2    = (const float*)d_in[7];
  const float* w_fc1 = (const float*)d_in[8];
  const float* b_fc1 = (const float*)d_in[9];
  const float* w_fc2 = (const float*)d_in[10];
  const float* b_fc2 = (const float*)d_in[11];
  float* out = (float*)d_out;
  char* ws = (char*)d_ws;

  u16*   Wt1   = (u16*)  (ws + O_WT1);
  u16*   Wt2   = (u16*)  (ws + O_WT2);
  u16*   Hb    = (u16*)  (ws + O_H);
  float* modsb = (float*)(ws + O_MODS);
  float* kb    = (float*)(ws + O_K);
  float* vb    = (float*)(ws + O_V);
  float* ub    = (float*)(ws + O_U);
  float* A1b   = (float*)(ws + O_A1);
  float* S0b   = (float*)(ws + O_S0);
  float* S1b   = (float*)(ws + O_S1);
  float2* pb   = (float2*)(ws + O_P);
  u16*   actb  = (u16*)  (ws + O_ACT);

  // zero the padded B rows of Wt2 (rows 1152..1279)
  hipMemsetAsync(ws + O_WT2 + (size_t)HID*MLP*2, 0, (size_t)(NPAD2-HID)*MLP*2, stream);

  tcast_k<<<dim3(MLP/32, HID/32), dim3(32,8), 0, stream>>>(w_fc1, Wt1, HID, MLP);
  tcast_k<<<dim3(HID/32, MLP/32), dim3(32,8), 0, stream>>>(w_fc2, Wt2, MLP, HID);
  mods_k<<<dim3(27, NB), 256, 0, stream>>>(cvec, w_ada, b_ada, modsb);
  kv_k<<<dim3(9, 16), 256, 0, stream>>>(x, modsb, w1, b1, kb, vb);
  u_k<<<16, 256, 0, stream>>>(w2, kb, modsb, ub, A1b);
  sred_k<<<16, 256, 0, stream>>>(ub, A1b, modsb, b2, kb, S0b, S1b);
  p_k<<<MROWS/4, 256, 0, stream>>>(x, A1b, S0b, S1b, pb);
  h_k<<<MROWS/4, 256, 0, stream>>>(pb, vb, modsb, Hb);

  size_t actFull = (size_t)MROWS * MLP * 2;
  int nch = 1;
  while (nch < 8 && O_ACT + actFull/nch > ws_size) nch <<= 1;
  int rowsPer = MROWS / nch;

  for (int chn = 0; chn < nch; chn++){
    int r0 = chn * rowsPer;
    int nTm = rowsPer / 256;
    gemm8_k<0><<<nTm*(MLP/256), 512, 0, stream>>>(
        Hb + (size_t)r0*HID, Wt1, HID, MLP/256, b_fc1,
        actb, nullptr, nullptr, nullptr, nullptr, 0);
    gemm8_k<1><<<nTm*(NPAD2/256), 512, 0, stream>>>(
        actb, Wt2, MLP, NPAD2/256, b_fc2,
        nullptr, out, pb, vb, modsb, r0);
  }
  (void)in_sizes; (void)n_in; (void)out_size;
}

// Round 3
// 1194.401 us; speedup vs baseline: 1.2569x; 1.1938x over previous
//
#include <hip/hip_runtime.h>
#include <hip/hip_bf16.h>

#define DEV __device__ __forceinline__

typedef unsigned short u16;
typedef short short8 __attribute__((ext_vector_type(8)));
typedef float f32x4 __attribute__((ext_vector_type(4)));

constexpr int HID  = 1152;
constexpr int NSEQ = 4096;
constexpr int NB   = 8;
constexpr int MROWS = NB * NSEQ;      // 32768
constexpr int MLP  = 4608;
constexpr int NPAD2 = 1280;           // GEMM2 B rows padded to 5*256
constexpr float EPSV  = 1e-6f;
constexpr float SCALE = 0.11785113019775793f; // 72^-0.5

// ---- workspace layout (bytes) ----
constexpr size_t O_WT1  = 0;
constexpr size_t SZ_WT1 = (size_t)MLP * HID * 2;
constexpr size_t O_WT2  = O_WT1 + SZ_WT1;
constexpr size_t SZ_WT2 = (size_t)NPAD2 * MLP * 2;
constexpr size_t O_H    = O_WT2 + SZ_WT2;
constexpr size_t SZ_H   = (size_t)MROWS * HID * 2;
constexpr size_t O_MODS = O_H + SZ_H;
constexpr size_t O_K    = O_MODS + (size_t)NB*6912*4;
constexpr size_t O_V    = O_K + (size_t)16*HID*4;
constexpr size_t O_U    = O_V + (size_t)16*HID*4;
constexpr size_t O_A1   = O_U + (size_t)16*HID*4;
constexpr size_t O_S0   = O_A1 + (size_t)16*HID*4;
constexpr size_t O_S1   = O_S0 + 64;
constexpr size_t O_P    = O_S1 + 64;
constexpr size_t O_ACT  = O_P + (size_t)NB*NSEQ*2*4;

#define BARR  asm volatile("s_barrier" ::: "memory")
#define VMW0  asm volatile("s_waitcnt vmcnt(0)" ::: "memory")
#define VMW4  asm volatile("s_waitcnt vmcnt(4)" ::: "memory")
#define VMW8  asm volatile("s_waitcnt vmcnt(8)" ::: "memory")
#define SP1   __builtin_amdgcn_s_setprio(1)
#define SP0   __builtin_amdgcn_s_setprio(0)

DEV u16 f2bf(float f){
  __hip_bfloat16 h = __float2bfloat16(f);
  u16 u; __builtin_memcpy(&u, &h, 2); return u;
}

DEV float wsum(float v){
  #pragma unroll
  for (int o = 32; o; o >>= 1) v += __shfl_xor(v, o, 64);
  return v;
}

DEV void cp16(void* lds, const void* g){
  __builtin_amdgcn_global_load_lds(
      (__attribute__((address_space(1))) void*)g,
      (__attribute__((address_space(3))) void*)lds, 16, 0, 0);
}

// ---------------- transpose + cast fp32 (K,N) -> bf16 (N,K) ----------------
__global__ void tcast_k(const float* __restrict__ in, u16* __restrict__ out, int K, int N){
  __shared__ float tile[32][33];
  int n0 = blockIdx.x * 32, k0 = blockIdx.y * 32;
  int tx = threadIdx.x, ty = threadIdx.y;
  #pragma unroll
  for (int i = 0; i < 32; i += 8)
    tile[ty + i][tx] = in[(size_t)(k0 + ty + i) * N + (n0 + tx)];
  __syncthreads();
  #pragma unroll
  for (int i = 0; i < 32; i += 8)
    out[(size_t)(n0 + ty + i) * K + (k0 + tx)] = f2bf(tile[tx][ty + i]);
}

// ---------------- mods = silu(c) @ w_ada + b_ada ----------------
__global__ void mods_k(const float* __restrict__ cv, const float* __restrict__ w_ada,
                       const float* __restrict__ b_ada, float* __restrict__ modsb){
  int b = blockIdx.y;
  __shared__ float cs[HID];
  int tid = threadIdx.x;
  for (int i = tid; i < HID; i += 256){
    float t = cv[b*HID + i];
    cs[i] = t / (1.f + __expf(-t));
  }
  __syncthreads();
  int col = blockIdx.x * 256 + tid;
  float acc = b_ada[col];
  #pragma unroll 4
  for (int k = 0; k < HID; k++) acc += cs[k] * w_ada[(size_t)k*6912 + col];
  modsb[b*6912 + col] = acc;
}

// ---------------- kv = modulate(ln(x0)) @ w1 + b1 ----------------
__global__ void kv_k(const float* __restrict__ x, const float* __restrict__ modsb,
                     const float* __restrict__ w1, const float* __restrict__ b1,
                     float* __restrict__ kbuf, float* __restrict__ vbuf){
  int bt = blockIdx.y; int b = bt >> 1, t = bt & 1;
  int tid = threadIdx.x;
  __shared__ float mx[HID];
  __shared__ float rbuf[8];
  __shared__ float s_mu, s_rs;
  const float* xr = x + ((size_t)b*NSEQ + t) * HID;
  float sx = 0.f, sxx = 0.f;
  for (int i = tid; i < HID; i += 256){ float v = xr[i]; sx += v; sxx += v*v; }
  sx = wsum(sx); sxx = wsum(sxx);
  int wave = tid >> 6, lane = tid & 63;
  if (lane == 0){ rbuf[wave] = sx; rbuf[4+wave] = sxx; }
  __syncthreads();
  if (tid == 0){
    float a = rbuf[0]+rbuf[1]+rbuf[2]+rbuf[3];
    float bb = rbuf[4]+rbuf[5]+rbuf[6]+rbuf[7];
    float mu = a * (1.f/HID);
    float var = bb * (1.f/HID) - mu*mu;
    s_mu = mu; s_rs = rsqrtf(var + EPSV);
  }
  __syncthreads();
  float mu = s_mu, rs = s_rs;
  const float* md = modsb + b*6912;
  for (int i = tid; i < HID; i += 256)
    mx[i] = (xr[i]-mu)*rs*(1.f + md[HID+i]) + md[i];
  __syncthreads();
  int col = blockIdx.x * 256 + tid;
  float acc = b1[col];
  #pragma unroll 4
  for (int k = 0; k < HID; k++) acc += mx[k] * w1[(size_t)k*2304 + col];
  if (col < HID) kbuf[bt*HID + col] = acc;
  else           vbuf[bt*HID + col - HID] = acc;
}

// ---------------- u = W2 k ; A1 = (1+sc_msa)*u  (one wave per output row) ----------------
__global__ void u2_k(const float* __restrict__ w2, const float* __restrict__ kbuf,
                     const float* __restrict__ modsb, float* __restrict__ ub,
                     float* __restrict__ A1b){
  int bm = blockIdx.y; int b = bm >> 1;
  int tid = threadIdx.x, wave = tid >> 6, lane = tid & 63;
  __shared__ float ks[HID];
  for (int i = tid; i < HID; i += 256) ks[i] = kbuf[bm*HID + i];
  __syncthreads();
  const float* md = modsb + b*6912;
  int j0 = blockIdx.x*16 + wave*4;
  #pragma unroll
  for (int jj = 0; jj < 4; jj++){
    int j = j0 + jj;
    const float* wr = w2 + (size_t)j*HID;
    float acc = 0.f;
    for (int i = lane; i < HID; i += 64) acc += wr[i] * ks[i];
    acc = wsum(acc);
    if (lane == 0){
      ub[bm*HID + j] = acc;
      A1b[bm*HID + j] = (1.f + md[HID + j]) * acc;
    }
  }
}

// ---------------- S1 = sum A1; S0 = sum sh_msa*u + sum b2*k ----------------
__global__ void sred_k(const float* __restrict__ ub, const float* __restrict__ A1b,
                       const float* __restrict__ modsb, const float* __restrict__ b2,
                       const float* __restrict__ kbuf, float* __restrict__ S0,
                       float* __restrict__ S1){
  int bm = blockIdx.x; int b = bm >> 1;
  int tid = threadIdx.x;
  float s0 = 0.f, s1 = 0.f;
  const float* md = modsb + b*6912;
  for (int i = tid; i < HID; i += 256){
    s1 += A1b[bm*HID + i];
    s0 += md[i]*ub[bm*HID + i] + b2[i]*kbuf[bm*HID + i];
  }
  s0 = wsum(s0); s1 = wsum(s1);
  __shared__ float rb[16];
  int wave = tid >> 6, lane = tid & 63;
  if (lane == 0){ rb[wave] = s0; rb[8+wave] = s1; }
  __syncthreads();
  if (tid == 0){
    S0[bm] = rb[0]+rb[1]+rb[2]+rb[3];
    S1[bm] = rb[8]+rb[9]+rb[10]+rb[11];
  }
}

// ---------------- p = softmax over 2 keys ----------------
__global__ void p_k(const float* __restrict__ x, const float* __restrict__ A1b,
                    const float* __restrict__ S0, const float* __restrict__ S1,
                    float2* __restrict__ pb){
  int tid = threadIdx.x, wave = tid >> 6, lane = tid & 63;
  int row0 = blockIdx.x * 4;
  int b = row0 >> 12;
  __shared__ float a1s[2*HID];
  for (int i = tid; i < 2*HID; i += 256) a1s[i] = A1b[b*2*HID + i];
  __syncthreads();
  int row = row0 + wave;
  const float* xr = x + (size_t)row * HID;
  float sx = 0.f, sxx = 0.f, d0 = 0.f, d1 = 0.f;
  #pragma unroll
  for (int i = 0; i < 9; i++){
    int cc = lane*2 + i*128;
    float2 v = *(const float2*)(xr + cc);
    sx += v.x + v.y; sxx += v.x*v.x + v.y*v.y;
    d0 += v.x*a1s[cc]       + v.y*a1s[cc+1];
    d1 += v.x*a1s[HID+cc]   + v.y*a1s[HID+cc+1];
  }
  sx = wsum(sx); sxx = wsum(sxx); d0 = wsum(d0); d1 = wsum(d1);
  if (lane == 0){
    float mu = sx * (1.f/HID);
    float var = sxx * (1.f/HID) - mu*mu;
    float rs = rsqrtf(var + EPSV);
    float sc0 = rs*(d0 - mu*S1[b*2+0]) + S0[b*2+0];
    float sc1 = rs*(d1 - mu*S1[b*2+1]) + S0[b*2+1];
    float z = (sc0 - sc1) * SCALE;
    float p0 = 1.f / (1.f + __expf(-z));
    pb[row] = make_float2(p0, 1.f - p0);
  }
}

// ---------------- H = bf16( modulate(ln(y2), sh_mlp, sc_mlp) ) ----------------
__global__ void h_k(const float2* __restrict__ pb, const float* __restrict__ vbuf,
                    const float* __restrict__ modsb, u16* __restrict__ H){
  int tid = threadIdx.x, wave = tid >> 6, lane = tid & 63;
  int row0 = blockIdx.x * 4;
  int b = row0 >> 12;
  __shared__ float gs[HID], shs[HID], scs[HID];
  const float* md = modsb + b*6912;
  for (int i = tid; i < HID; i += 256){
    gs[i]  = 1.f + md[2*HID + i];
    shs[i] = md[3*HID + i];
    scs[i] = 1.f + md[4*HID + i];
  }
  __syncthreads();
  int row = row0 + wave;
  int n = row & (NSEQ-1);
  const float2* pbb = pb + ((size_t)b << 12);
  const float* vb0 = vbuf + b*2*HID;
  float yv[18];
  float sx = 0.f, sxx = 0.f;
  #pragma unroll
  for (int i = 0; i < 9; i++){
    int cc = lane*2 + i*128;
    int f = n*HID + cc;
    int r0 = f & (NSEQ-1), ci0 = f >> 12;
    int f1 = f + 1;
    int r1 = f1 & (NSEQ-1), ci1 = f1 >> 12;
    float2 pv0 = pbb[r0];
    float2 pv1 = pbb[r1];
    float y0 = gs[cc]   * (pv0.x*vb0[ci0] + pv0.y*vb0[HID+ci0]);
    float y1 = gs[cc+1] * (pv1.x*vb0[ci1] + pv1.y*vb0[HID+ci1]);
    yv[2*i] = y0; yv[2*i+1] = y1;
    sx += y0 + y1; sxx += y0*y0 + y1*y1;
  }
  sx = wsum(sx); sxx = wsum(sxx);
  float mu = sx * (1.f/HID);
  float var = sxx * (1.f/HID) - mu*mu;
  float rs = rsqrtf(var + EPSV);
  u16* Hr = H + (size_t)row * HID;
  #pragma unroll
  for (int i = 0; i < 9; i++){
    int cc = lane*2 + i*128;
    ushort2 st;
    st.x = f2bf((yv[2*i]   - mu)*rs*scs[cc]   + shs[cc]);
    st.y = f2bf((yv[2*i+1] - mu)*rs*scs[cc+1] + shs[cc+1]);
    *(ushort2*)(Hr + cc) = st;
  }
}

// =========== 256x256 8-phase bf16 MFMA GEMM (T2+T3+T4+T5), BK=64 ===========
// EPI 0: outB = bf16(gelu_tanh(acc+bias)), coalesced via LDS restage
// EPI 1: outF = y2 + g_mlp*(acc+bias), cols masked < HID
template<int EPI>
__global__ __launch_bounds__(512, 2) void gemm8_k(
    const u16* __restrict__ A, const u16* __restrict__ Bt,
    int K, int nTn,
    const float* __restrict__ bias,
    u16* __restrict__ outB, float* __restrict__ outF,
    const float2* __restrict__ p, const float* __restrict__ vbuf,
    const float* __restrict__ modsb, int rowOffset)
{
  __shared__ u16 lds[2][2][256*64];
  const int tid = threadIdx.x;
  const int wave = tid >> 6, lane = tid & 63;
  const int wm = wave >> 2, wn = wave & 3;

  // bijective XCD swizzle (nwg % 8 == 0 by launch config)
  int nwg = gridDim.x;
  int bid = blockIdx.x;
  int q = nwg >> 3;
  int w = (bid & 7) * q + (bid >> 3);
  int bm = w / nTn, bn = w - bm * nTn;

  const u16* Ab = A + (size_t)bm * 256 * K;
  const u16* Bb = Bt + (size_t)bn * 256 * K;

  f32x4 acc[8][4] = {};

  auto stage = [&](int buf, int ab, int half, int t){
    const u16* src = ab ? Bb : Ab;
    char* ldsb = (char*)&lds[buf][ab][0] + half*16384 + wave*2048 + lane*16;
    int rbase = half*128 + wave*16 + (lane>>3);
    int kof = t*64 + (((lane&7) ^ (lane>>3)) << 3);
    cp16(ldsb,        src + (size_t)rbase*K + kof);
    cp16(ldsb + 1024, src + (size_t)(rbase+8)*K + kof);
  };
  auto ldA = [&](short8 (&v)[4][2], int buf, int mh){
    const char* base = (const char*)&lds[buf][0][0];
    int colb = (((lane>>4)<<4)) ^ ((lane&7)<<4);
    #pragma unroll
    for (int f = 0; f < 4; f++){
      const char* rp = base + (wm*128 + mh*64 + f*16 + (lane&15))*128;
      v[f][0] = *(const short8*)(rp + colb);
      v[f][1] = *(const short8*)(rp + (colb ^ 64));
    }
  };
  auto ldB = [&](short8 (&v)[2][2], int buf, int nh){
    const char* base = (const char*)&lds[buf][1][0];
    int colb = (((lane>>4)<<4)) ^ ((lane&7)<<4);
    #pragma unroll
    for (int f = 0; f < 2; f++){
      const char* rp = base + (wn*64 + nh*32 + f*16 + (lane&15))*128;
      v[f][0] = *(const short8*)(rp + colb);
      v[f][1] = *(const short8*)(rp + (colb ^ 64));
    }
  };
  auto mm = [&](short8 (&a)[4][2], short8 (&b)[2][2], int mh, int nh){
    #pragma unroll
    for (int ks = 0; ks < 2; ks++)
      #pragma unroll
      for (int f = 0; f < 4; f++)
        #pragma unroll
        for (int g = 0; g < 2; g++)
          acc[mh*4+f][nh*2+g] = __builtin_amdgcn_mfma_f32_16x16x32_bf16(
              a[f][ks], b[g][ks], acc[mh*4+f][nh*2+g], 0, 0, 0);
  };

  short8 av[4][2], av2[4][2], bv[2][2], bv2[2][2];

  stage(0,0,0,0); stage(0,0,1,0); stage(0,1,0,0); stage(0,1,1,0);
  stage(1,1,0,1); stage(1,1,1,1); stage(1,0,0,1); stage(1,0,1,1);
  VMW8; BARR;

  const int NIT = K >> 7;
  for (int it = 0; it < NIT; ++it){
    const int t2 = 2*it + 2, t3 = 2*it + 3;
    const bool fin = (it == NIT-1);
    ldA(av, 0, 0); ldB(bv, 0, 0);
    BARR; SP1; mm(av, bv, 0, 0); SP0; BARR;
    ldB(bv2, 0, 1);
    BARR; SP1; mm(av, bv2, 0, 1); SP0; BARR;
    ldA(av2, 0, 1);
    if (!fin) stage(0,1,0,t2);
    BARR; SP1; mm(av2, bv, 1, 0); SP0; BARR;
    if (!fin){ stage(0,1,1,t2); VMW4; } else { VMW0; }
    BARR; SP1; mm(av2, bv2, 1, 1); SP0; BARR;
    ldA(av, 1, 0); ldB(bv, 1, 0);
    if (!fin){ stage(0,0,0,t2); stage(0,0,1,t2); }
    BARR; SP1; mm(av, bv, 0, 0); SP0; BARR;
    ldB(bv2, 1, 1);
    BARR; SP1; mm(av, bv2, 0, 1); SP0; BARR;
    ldA(av2, 1, 1);
    if (!fin) stage(1,1,0,t3);
    BARR; SP1; mm(av2, bv, 1, 0); SP0; BARR;
    if (!fin){ stage(1,1,1,t3); stage(1,0,0,t3); stage(1,0,1,t3); VMW8; }
    BARR; SP1; mm(av2, bv2, 1, 1); SP0; BARR;
  }

  int colBase = bn*256 + wn*64;
  int rowB = bm*256 + wm*128 + ((lane>>4)<<2);
  if constexpr (EPI == 0){
    // gelu in-register -> swizzled LDS restage -> coalesced dwordx4 stores
    u16* cs = (u16*)&lds[0][0][0];
    #pragma unroll
    for (int n = 0; n < 4; n++){
      int colL = wn*64 + n*16 + (lane&15);
      float bs = bias[bn*256 + colL];
      #pragma unroll
      for (int m = 0; m < 8; m++){
        #pragma unroll
        for (int r = 0; r < 4; r++){
          int rowL = wm*128 + m*16 + ((lane>>4)<<2) + r;
          float xv = acc[m][n][r] + bs;
          float t = xv * (1.f + 0.044715f * xv * xv);
          float g = xv / (1.f + __expf(-1.5957691216057308f * t));
          int bo = ((rowL*256 + colL)*2) ^ (((rowL>>2)&3)<<5);
          *(u16*)((char*)cs + bo) = f2bf(g);
        }
      }
    }
    __syncthreads();
    #pragma unroll
    for (int e = 0; e < 16; e++){
      int idx = e*512 + tid;
      int rowL = idx >> 5, c16 = idx & 31;
      int bo = (rowL*512 + c16*16) ^ (((rowL>>2)&3)<<5);
      ulonglong2 v = *(const ulonglong2*)((const char*)cs + bo);
      *(ulonglong2*)&outB[(size_t)(bm*256 + rowL)*MLP + bn*256 + c16*8] = v;
    }
  } else {
    int bIdx = (rowOffset + bm*256) >> 12;
    const float* md = modsb + bIdx*6912;
    const float2* pbb = p + ((size_t)bIdx << 12);
    const float* vb0 = vbuf + bIdx*2*HID;
    #pragma unroll
    for (int n = 0; n < 4; n++){
      int col = colBase + n*16 + (lane&15);
      if (col < HID){
        float bs = bias[col];
        float gmsa = 1.f + md[2*HID + col];
        float gmlp = md[5*HID + col];
        #pragma unroll
        for (int m = 0; m < 8; m++){
          #pragma unroll
          for (int r = 0; r < 4; r++){
            int grow = rowOffset + rowB + m*16 + r;
            int nn = grow & (NSEQ-1);
            int f = nn*HID + col;
            int rr = f & (NSEQ-1), ci = f >> 12;
            float2 pv = pbb[rr];
            float y2 = gmsa * (pv.x*vb0[ci] + pv.y*vb0[HID + ci]);
            outF[(size_t)grow*HID + col] = y2 + gmlp * (acc[m][n][r] + bs);
          }
        }
      }
    }
  }
}

extern "C" void kernel_launch(void* const* d_in, const int* in_sizes, int n_in,
                              void* d_out, int out_size, void* d_ws, size_t ws_size,
                              hipStream_t stream){
  const float* x     = (const float*)d_in[0];
  const float* cvec  = (const float*)d_in[1];
  const float* w_ada = (const float*)d_in[2];
  const float* b_ada = (const float*)d_in[3];
  const float* w1    = (const float*)d_in[4];
  const float* b1    = (const float*)d_in[5];
  const float* w2    = (const float*)d_in[6];
  const float* b2    = (const float*)d_in[7];
  const float* w_fc1 = (const float*)d_in[8];
  const float* b_fc1 = (const float*)d_in[9];
  const float* w_fc2 = (const float*)d_in[10];
  const float* b_fc2 = (const float*)d_in[11];
  float* out = (float*)d_out;
  char* ws = (char*)d_ws;

  u16*   Wt1   = (u16*)  (ws + O_WT1);
  u16*   Wt2   = (u16*)  (ws + O_WT2);
  u16*   Hb    = (u16*)  (ws + O_H);
  float* modsb = (float*)(ws + O_MODS);
  float* kb    = (float*)(ws + O_K);
  float* vb    = (float*)(ws + O_V);
  float* ub    = (float*)(ws + O_U);
  float* A1b   = (float*)(ws + O_A1);
  float* S0b   = (float*)(ws + O_S0);
  float* S1b   = (float*)(ws + O_S1);
  float2* pb   = (float2*)(ws + O_P);
  u16*   actb  = (u16*)  (ws + O_ACT);

  hipMemsetAsync(ws + O_WT2 + (size_t)HID*MLP*2, 0, (size_t)(NPAD2-HID)*MLP*2, stream);

  tcast_k<<<dim3(MLP/32, HID/32), dim3(32,8), 0, stream>>>(w_fc1, Wt1, HID, MLP);
  tcast_k<<<dim3(HID/32, MLP/32), dim3(32,8), 0, stream>>>(w_fc2, Wt2, MLP, HID);
  mods_k<<<dim3(27, NB), 256, 0, stream>>>(cvec, w_ada, b_ada, modsb);
  kv_k<<<dim3(9, 16), 256, 0, stream>>>(x, modsb, w1, b1, kb, vb);
  u2_k<<<dim3(HID/16, 16), 256, 0, stream>>>(w2, kb, modsb, ub, A1b);
  sred_k<<<16, 256, 0, stream>>>(ub, A1b, modsb, b2, kb, S0b, S1b);
  p_k<<<MROWS/4, 256, 0, stream>>>(x, A1b, S0b, S1b, pb);
  h_k<<<MROWS/4, 256, 0, stream>>>(pb, vb, modsb, Hb);

  size_t actFull = (size_t)MROWS * MLP * 2;
  int nch = 1;
  while (nch < 8 && O_ACT + actFull/nch > ws_size) nch <<= 1;
  int rowsPer = MROWS / nch;

  for (int chn = 0; chn < nch; chn++){
    int r0 = chn * rowsPer;
    int nTm = rowsPer / 256;
    gemm8_k<0><<<nTm*(MLP/256), 512, 0, stream>>>(
        Hb + (size_t)r0*HID, Wt1, HID, MLP/256, b_fc1,
        actb, nullptr, nullptr, nullptr, nullptr, 0);
    gemm8_k<1><<<nTm*(NPAD2/256), 512, 0, stream>>>(
        actb, Wt2, MLP, NPAD2/256, b_fc2,
        nullptr, out, pb, vb, modsb, r0);
  }
  (void)in_sizes; (void)n_in; (void)out_size;
}

// Round 5
// 1118.275 us; speedup vs baseline: 1.3424x; 1.0681x over previous
//
#include <hip/hip_runtime.h>
#include <hip/hip_bf16.h>

#define DEV __device__ __forceinline__

typedef unsigned short u16;
typedef short short8 __attribute__((ext_vector_type(8)));
typedef float f32x4 __attribute__((ext_vector_type(4)));
typedef unsigned long long ulv2 __attribute__((ext_vector_type(2)));

constexpr int HID  = 1152;
constexpr int NSEQ = 4096;
constexpr int NB   = 8;
constexpr int MROWS = NB * NSEQ;      // 32768
constexpr int MLP  = 4608;
constexpr int NPAD2 = 1280;           // GEMM2 B rows padded to 5*256
constexpr float EPSV  = 1e-6f;
constexpr float SCALE = 0.11785113019775793f; // 72^-0.5

// ---- workspace layout (bytes) ----
constexpr size_t O_WT1  = 0;
constexpr size_t SZ_WT1 = (size_t)MLP * HID * 2;
constexpr size_t O_WT2  = O_WT1 + SZ_WT1;
constexpr size_t SZ_WT2 = (size_t)NPAD2 * MLP * 2;
constexpr size_t O_H    = O_WT2 + SZ_WT2;
constexpr size_t SZ_H   = (size_t)MROWS * HID * 2;
constexpr size_t O_MODS = O_H + SZ_H;
constexpr size_t O_K    = O_MODS + (size_t)NB*6912*4;
constexpr size_t O_V    = O_K + (size_t)16*HID*4;
constexpr size_t O_U    = O_V + (size_t)16*HID*4;
constexpr size_t O_A1   = O_U + (size_t)16*HID*4;
constexpr size_t O_S0   = O_A1 + (size_t)16*HID*4;
constexpr size_t O_S1   = O_S0 + 64;
constexpr size_t O_P    = O_S1 + 64;
constexpr size_t O_ACT  = O_P + (size_t)NB*NSEQ*2*4;

#define BARR  asm volatile("s_barrier" ::: "memory")
#define VMW0  asm volatile("s_waitcnt vmcnt(0)" ::: "memory")
#define VMW4  asm volatile("s_waitcnt vmcnt(4)" ::: "memory")
#define VMW8  asm volatile("s_waitcnt vmcnt(8)" ::: "memory")
#define SP1   __builtin_amdgcn_s_setprio(1)
#define SP0   __builtin_amdgcn_s_setprio(0)

DEV u16 f2bf(float f){
  __hip_bfloat16 h = __float2bfloat16(f);
  u16 u; __builtin_memcpy(&u, &h, 2); return u;
}

DEV float wsum(float v){
  #pragma unroll
  for (int o = 32; o; o >>= 1) v += __shfl_xor(v, o, 64);
  return v;
}

DEV void cp16(void* lds, const void* g){
  __builtin_amdgcn_global_load_lds(
      (__attribute__((address_space(1))) void*)g,
      (__attribute__((address_space(3))) void*)lds, 16, 0, 0);
}

// ---------------- transpose + cast fp32 (K,N) -> bf16 (N,K) ----------------
__global__ void tcast_k(const float* __restrict__ in, u16* __restrict__ out, int K, int N){
  __shared__ float tile[32][33];
  int n0 = blockIdx.x * 32, k0 = blockIdx.y * 32;
  int tx = threadIdx.x, ty = threadIdx.y;
  #pragma unroll
  for (int i = 0; i < 32; i += 8)
    tile[ty + i][tx] = in[(size_t)(k0 + ty + i) * N + (n0 + tx)];
  __syncthreads();
  #pragma unroll
  for (int i = 0; i < 32; i += 8)
    out[(size_t)(n0 + ty + i) * K + (k0 + tx)] = f2bf(tile[tx][ty + i]);
}

// ---------------- mods = silu(c) @ w_ada + b_ada ----------------
__global__ void mods_k(const float* __restrict__ cv, const float* __restrict__ w_ada,
                       const float* __restrict__ b_ada, float* __restrict__ modsb){
  int b = blockIdx.y;
  __shared__ float cs[HID];
  int tid = threadIdx.x;
  for (int i = tid; i < HID; i += 256){
    float t = cv[b*HID + i];
    cs[i] = t / (1.f + __expf(-t));
  }
  __syncthreads();
  int col = blockIdx.x * 256 + tid;
  float acc = b_ada[col];
  #pragma unroll 4
  for (int k = 0; k < HID; k++) acc += cs[k] * w_ada[(size_t)k*6912 + col];
  modsb[b*6912 + col] = acc;
}

// ---------------- kv = modulate(ln(x0)) @ w1 + b1 ----------------
__global__ void kv_k(const float* __restrict__ x, const float* __restrict__ modsb,
                     const float* __restrict__ w1, const float* __restrict__ b1,
                     float* __restrict__ kbuf, float* __restrict__ vbuf){
  int bt = blockIdx.y; int b = bt >> 1, t = bt & 1;
  int tid = threadIdx.x;
  __shared__ float mx[HID];
  __shared__ float rbuf[8];
  __shared__ float s_mu, s_rs;
  const float* xr = x + ((size_t)b*NSEQ + t) * HID;
  float sx = 0.f, sxx = 0.f;
  for (int i = tid; i < HID; i += 256){ float v = xr[i]; sx += v; sxx += v*v; }
  sx = wsum(sx); sxx = wsum(sxx);
  int wave = tid >> 6, lane = tid & 63;
  if (lane == 0){ rbuf[wave] = sx; rbuf[4+wave] = sxx; }
  __syncthreads();
  if (tid == 0){
    float a = rbuf[0]+rbuf[1]+rbuf[2]+rbuf[3];
    float bb = rbuf[4]+rbuf[5]+rbuf[6]+rbuf[7];
    float mu = a * (1.f/HID);
    float var = bb * (1.f/HID) - mu*mu;
    s_mu = mu; s_rs = rsqrtf(var + EPSV);
  }
  __syncthreads();
  float mu = s_mu, rs = s_rs;
  const float* md = modsb + b*6912;
  for (int i = tid; i < HID; i += 256)
    mx[i] = (xr[i]-mu)*rs*(1.f + md[HID+i]) + md[i];
  __syncthreads();
  int col = blockIdx.x * 256 + tid;
  float acc = b1[col];
  #pragma unroll 4
  for (int k = 0; k < HID; k++) acc += mx[k] * w1[(size_t)k*2304 + col];
  if (col < HID) kbuf[bt*HID + col] = acc;
  else           vbuf[bt*HID + col - HID] = acc;
}

// ---------------- u = W2 k ; A1 = (1+sc_msa)*u  (one wave per output row) ----------------
__global__ void u2_k(const float* __restrict__ w2, const float* __restrict__ kbuf,
                     const float* __restrict__ modsb, float* __restrict__ ub,
                     float* __restrict__ A1b){
  int bm = blockIdx.y; int b = bm >> 1;
  int tid = threadIdx.x, wave = tid >> 6, lane = tid & 63;
  __shared__ float ks[HID];
  for (int i = tid; i < HID; i += 256) ks[i] = kbuf[bm*HID + i];
  __syncthreads();
  const float* md = modsb + b*6912;
  int j0 = blockIdx.x*16 + wave*4;
  #pragma unroll
  for (int jj = 0; jj < 4; jj++){
    int j = j0 + jj;
    const float* wr = w2 + (size_t)j*HID;
    float acc = 0.f;
    for (int i = lane; i < HID; i += 64) acc += wr[i] * ks[i];
    acc = wsum(acc);
    if (lane == 0){
      ub[bm*HID + j] = acc;
      A1b[bm*HID + j] = (1.f + md[HID + j]) * acc;
    }
  }
}

// ---------------- S1 = sum A1; S0 = sum sh_msa*u + sum b2*k ----------------
__global__ void sred_k(const float* __restrict__ ub, const float* __restrict__ A1b,
                       const float* __restrict__ modsb, const float* __restrict__ b2,
                       const float* __restrict__ kbuf, float* __restrict__ S0,
                       float* __restrict__ S1){
  int bm = blockIdx.x; int b = bm >> 1;
  int tid = threadIdx.x;
  float s0 = 0.f, s1 = 0.f;
  const float* md = modsb + b*6912;
  for (int i = tid; i < HID; i += 256){
    s1 += A1b[bm*HID + i];
    s0 += md[i]*ub[bm*HID + i] + b2[i]*kbuf[bm*HID + i];
  }
  s0 = wsum(s0); s1 = wsum(s1);
  __shared__ float rb[16];
  int wave = tid >> 6, lane = tid & 63;
  if (lane == 0){ rb[wave] = s0; rb[8+wave] = s1; }
  __syncthreads();
  if (tid == 0){
    S0[bm] = rb[0]+rb[1]+rb[2]+rb[3];
    S1[bm] = rb[8]+rb[9]+rb[10]+rb[11];
  }
}

// ---------------- p = softmax over 2 keys ----------------
__global__ void p_k(const float* __restrict__ x, const float* __restrict__ A1b,
                    const float* __restrict__ S0, const float* __restrict__ S1,
                    float2* __restrict__ pb){
  int tid = threadIdx.x, wave = tid >> 6, lane = tid & 63;
  int row0 = blockIdx.x * 4;
  int b = row0 >> 12;
  __shared__ float a1s[2*HID];
  for (int i = tid; i < 2*HID; i += 256) a1s[i] = A1b[b*2*HID + i];
  __syncthreads();
  int row = row0 + wave;
  const float* xr = x + (size_t)row * HID;
  float sx = 0.f, sxx = 0.f, d0 = 0.f, d1 = 0.f;
  #pragma unroll
  for (int i = 0; i < 9; i++){
    int cc = lane*2 + i*128;
    float2 v = *(const float2*)(xr + cc);
    sx += v.x + v.y; sxx += v.x*v.x + v.y*v.y;
    d0 += v.x*a1s[cc]       + v.y*a1s[cc+1];
    d1 += v.x*a1s[HID+cc]   + v.y*a1s[HID+cc+1];
  }
  sx = wsum(sx); sxx = wsum(sxx); d0 = wsum(d0); d1 = wsum(d1);
  if (lane == 0){
    float mu = sx * (1.f/HID);
    float var = sxx * (1.f/HID) - mu*mu;
    float rs = rsqrtf(var + EPSV);
    float sc0 = rs*(d0 - mu*S1[b*2+0]) + S0[b*2+0];
    float sc1 = rs*(d1 - mu*S1[b*2+1]) + S0[b*2+1];
    float z = (sc0 - sc1) * SCALE;
    float p0 = 1.f / (1.f + __expf(-z));
    pb[row] = make_float2(p0, 1.f - p0);
  }
}

// ---------------- H = bf16( modulate(ln(y2), sh_mlp, sc_mlp) ) ----------------
__global__ void h_k(const float2* __restrict__ pb, const float* __restrict__ vbuf,
                    const float* __restrict__ modsb, u16* __restrict__ H){
  int tid = threadIdx.x, wave = tid >> 6, lane = tid & 63;
  int row0 = blockIdx.x * 4;
  int b = row0 >> 12;
  __shared__ float gs[HID], shs[HID], scs[HID];
  const float* md = modsb + b*6912;
  for (int i = tid; i < HID; i += 256){
    gs[i]  = 1.f + md[2*HID + i];
    shs[i] = md[3*HID + i];
    scs[i] = 1.f + md[4*HID + i];
  }
  __syncthreads();
  int row = row0 + wave;
  int n = row & (NSEQ-1);
  const float2* pbb = pb + ((size_t)b << 12);
  const float* vb0 = vbuf + b*2*HID;
  float yv[18];
  float sx = 0.f, sxx = 0.f;
  #pragma unroll
  for (int i = 0; i < 9; i++){
    int cc = lane*2 + i*128;
    int f = n*HID + cc;
    int r0 = f & (NSEQ-1), ci0 = f >> 12;
    int f1 = f + 1;
    int r1 = f1 & (NSEQ-1), ci1 = f1 >> 12;
    float2 pv0 = pbb[r0];
    float2 pv1 = pbb[r1];
    float y0 = gs[cc]   * (pv0.x*vb0[ci0] + pv0.y*vb0[HID+ci0]);
    float y1 = gs[cc+1] * (pv1.x*vb0[ci1] + pv1.y*vb0[HID+ci1]);
    yv[2*i] = y0; yv[2*i+1] = y1;
    sx += y0 + y1; sxx += y0*y0 + y1*y1;
  }
  sx = wsum(sx); sxx = wsum(sxx);
  float mu = sx * (1.f/HID);
  float var = sxx * (1.f/HID) - mu*mu;
  float rs = rsqrtf(var + EPSV);
  u16* Hr = H + (size_t)row * HID;
  #pragma unroll
  for (int i = 0; i < 9; i++){
    int cc = lane*2 + i*128;
    ushort2 st;
    st.x = f2bf((yv[2*i]   - mu)*rs*scs[cc]   + shs[cc]);
    st.y = f2bf((yv[2*i+1] - mu)*rs*scs[cc+1] + shs[cc+1]);
    *(ushort2*)(Hr + cc) = st;
  }
}

// =========== 256x256 8-phase bf16 MFMA GEMM, BK=64, compile-time K ===========
// One barrier per phase (post-MFMA); hazards guarded by in-phase lgkm drains +
// VMW->barrier->read chains. Non-temporal stores to keep L2/L3 clean.
template<int EPI, int KC>
__global__ __launch_bounds__(512, 2) void gemm8_k(
    const u16* __restrict__ A, const u16* __restrict__ Bt,
    int nTn,
    const float* __restrict__ bias,
    u16* __restrict__ outB, float* __restrict__ outF,
    const float2* __restrict__ p, const float* __restrict__ vbuf,
    const float* __restrict__ modsb, int rowOffset)
{
  __shared__ u16 lds[2][2][256*64];
  const int tid = threadIdx.x;
  const int wave = tid >> 6, lane = tid & 63;
  const int wm = wave >> 2, wn = wave & 3;

  // bijective XCD swizzle (nwg % 8 == 0 by launch config)
  int nwg = gridDim.x;
  int bid = blockIdx.x;
  int q = nwg >> 3;
  int w = (bid & 7) * q + (bid >> 3);
  int bm = w / nTn, bn = w - bm * nTn;

  const u16* Ab = A + (size_t)bm * 256 * KC;
  const u16* Bb = Bt + (size_t)bn * 256 * KC;

  f32x4 acc[8][4] = {};

  auto stage = [&](int buf, int ab, int half, int t){
    const u16* src = ab ? Bb : Ab;
    char* ldsb = (char*)&lds[buf][ab][0] + half*16384 + wave*2048 + lane*16;
    int rbase = half*128 + wave*16 + (lane>>3);
    int kof = t*64 + (((lane&7) ^ (lane>>3)) << 3);
    cp16(ldsb,        src + (size_t)rbase*KC + kof);
    cp16(ldsb + 1024, src + (size_t)(rbase+8)*KC + kof);
  };
  auto ldA = [&](short8 (&v)[4][2], int buf, int mh){
    const char* base = (const char*)&lds[buf][0][0];
    int colb = (((lane>>4)<<4)) ^ ((lane&7)<<4);
    #pragma unroll
    for (int f = 0; f < 4; f++){
      const char* rp = base + (wm*128 + mh*64 + f*16 + (lane&15))*128;
      v[f][0] = *(const short8*)(rp + colb);
      v[f][1] = *(const short8*)(rp + (colb ^ 64));
    }
  };
  auto ldB = [&](short8 (&v)[2][2], int buf, int nh){
    const char* base = (const char*)&lds[buf][1][0];
    int colb = (((lane>>4)<<4)) ^ ((lane&7)<<4);
    #pragma unroll
    for (int f = 0; f < 2; f++){
      const char* rp = base + (wn*64 + nh*32 + f*16 + (lane&15))*128;
      v[f][0] = *(const short8*)(rp + colb);
      v[f][1] = *(const short8*)(rp + (colb ^ 64));
    }
  };
  auto mm = [&](short8 (&a)[4][2], short8 (&b)[2][2], int mh, int nh){
    #pragma unroll
    for (int ks = 0; ks < 2; ks++)
      #pragma unroll
      for (int f = 0; f < 4; f++)
        #pragma unroll
        for (int g = 0; g < 2; g++)
          acc[mh*4+f][nh*2+g] = __builtin_amdgcn_mfma_f32_16x16x32_bf16(
              a[f][ks], b[g][ks], acc[mh*4+f][nh*2+g], 0, 0, 0);
  };

  short8 av[4][2], av2[4][2], bv[2][2], bv2[2][2];

  stage(0,0,0,0); stage(0,0,1,0); stage(0,1,0,0); stage(0,1,1,0);
  stage(1,1,0,1); stage(1,1,1,1); stage(1,0,0,1); stage(1,0,1,1);
  VMW8; BARR;

  constexpr int NIT = KC >> 7;
  for (int it = 0; it < NIT; ++it){
    const int t2 = 2*it + 2, t3 = 2*it + 3;
    const bool fin = (it == NIT-1);
    // ph1
    ldA(av, 0, 0); ldB(bv, 0, 0);
    SP1; mm(av, bv, 0, 0); SP0; BARR;
    // ph2
    ldB(bv2, 0, 1);
    SP1; mm(av, bv2, 0, 1); SP0; BARR;
    // ph3
    ldA(av2, 0, 1);
    if (!fin) stage(0,1,0,t2);
    SP1; mm(av2, bv, 1, 0); SP0; BARR;
    // ph4 (counted wait: tile 2i+1 landed before ph5 reads buf1)
    if (!fin){ stage(0,1,1,t2); VMW4; } else { VMW0; }
    SP1; mm(av2, bv2, 1, 1); SP0; BARR;
    // ph5
    ldA(av, 1, 0); ldB(bv, 1, 0);
    if (!fin){ stage(0,0,0,t2); stage(0,0,1,t2); }
    SP1; mm(av, bv, 0, 0); SP0; BARR;
    // ph6
    ldB(bv2, 1, 1);
    SP1; mm(av, bv2, 0, 1); SP0; BARR;
    // ph7
    ldA(av2, 1, 1);
    if (!fin) stage(1,1,0,t3);
    SP1; mm(av2, bv, 1, 0); SP0; BARR;
    // ph8 (counted wait: tile 2i+2 landed before next ph1 reads buf0)
    if (!fin){ stage(1,1,1,t3); stage(1,0,0,t3); stage(1,0,1,t3); VMW8; }
    SP1; mm(av2, bv2, 1, 1); SP0; BARR;
  }

  int colBase = bn*256 + wn*64;
  int rowB = bm*256 + wm*128 + ((lane>>4)<<2);
  if constexpr (EPI == 0){
    // gelu in-register -> swizzled LDS restage -> coalesced nt dwordx4 stores
    u16* cs = (u16*)&lds[0][0][0];
    #pragma unroll
    for (int n = 0; n < 4; n++){
      int colL = wn*64 + n*16 + (lane&15);
      float bs = bias[bn*256 + colL];
      #pragma unroll
      for (int m = 0; m < 8; m++){
        #pragma unroll
        for (int r = 0; r < 4; r++){
          int rowL = wm*128 + m*16 + ((lane>>4)<<2) + r;
          float xv = acc[m][n][r] + bs;
          float t = xv * (1.f + 0.044715f * xv * xv);
          float g = xv / (1.f + __expf(-1.5957691216057308f * t));
          int bo = ((rowL*256 + colL)*2) ^ (((rowL>>2)&3)<<5);
          *(u16*)((char*)cs + bo) = f2bf(g);
        }
      }
    }
    __syncthreads();
    #pragma unroll
    for (int e = 0; e < 16; e++){
      int idx = e*512 + tid;
      int rowL = idx >> 5, c16 = idx & 31;
      int bo = (rowL*512 + c16*16) ^ (((rowL>>2)&3)<<5);
      ulv2 v = *(const ulv2*)((const char*)cs + bo);
      __builtin_nontemporal_store(v,
          (ulv2*)&outB[(size_t)(bm*256 + rowL)*MLP + bn*256 + c16*8]);
    }
  } else {
    int bIdx = (rowOffset + bm*256) >> 12;
    const float* md = modsb + bIdx*6912;
    const float2* pbb = p + ((size_t)bIdx << 12);
    const float* vb0 = vbuf + bIdx*2*HID;
    #pragma unroll
    for (int n = 0; n < 4; n++){
      int col = colBase + n*16 + (lane&15);
      if (col < HID){
        float bs = bias[col];
        float gmsa = 1.f + md[2*HID + col];
        float gmlp = md[5*HID + col];
        #pragma unroll
        for (int m = 0; m < 8; m++){
          #pragma unroll
          for (int r = 0; r < 4; r++){
            int grow = rowOffset + rowB + m*16 + r;
            int nn = grow & (NSEQ-1);
            int f = nn*HID + col;
            int rr = f & (NSEQ-1), ci = f >> 12;
            float2 pv = pbb[rr];
            float y2 = gmsa * (pv.x*vb0[ci] + pv.y*vb0[HID + ci]);
            __builtin_nontemporal_store(y2 + gmlp * (acc[m][n][r] + bs),
                &outF[(size_t)grow*HID + col]);
          }
        }
      }
    }
  }
}

extern "C" void kernel_launch(void* const* d_in, const int* in_sizes, int n_in,
                              void* d_out, int out_size, void* d_ws, size_t ws_size,
                              hipStream_t stream){
  const float* x     = (const float*)d_in[0];
  const float* cvec  = (const float*)d_in[1];
  const float* w_ada = (const float*)d_in[2];
  const float* b_ada = (const float*)d_in[3];
  const float* w1    = (const float*)d_in[4];
  const float* b1    = (const float*)d_in[5];
  const float* w2    = (const float*)d_in[6];
  const float* b2    = (const float*)d_in[7];
  const float* w_fc1 = (const float*)d_in[8];
  const float* b_fc1 = (const float*)d_in[9];
  const float* w_fc2 = (const float*)d_in[10];
  const float* b_fc2 = (const float*)d_in[11];
  float* out = (float*)d_out;
  char* ws = (char*)d_ws;

  u16*   Wt1   = (u16*)  (ws + O_WT1);
  u16*   Wt2   = (u16*)  (ws + O_WT2);
  u16*   Hb    = (u16*)  (ws + O_H);
  float* modsb = (float*)(ws + O_MODS);
  float* kb    = (float*)(ws + O_K);
  float* vb    = (float*)(ws + O_V);
  float* ub    = (float*)(ws + O_U);
  float* A1b   = (float*)(ws + O_A1);
  float* S0b   = (float*)(ws + O_S0);
  float* S1b   = (float*)(ws + O_S1);
  float2* pb   = (float2*)(ws + O_P);
  u16*   actb  = (u16*)  (ws + O_ACT);

  (void)hipMemsetAsync(ws + O_WT2 + (size_t)HID*MLP*2, 0, (size_t)(NPAD2-HID)*MLP*2, stream);

  tcast_k<<<dim3(MLP/32, HID/32), dim3(32,8), 0, stream>>>(w_fc1, Wt1, HID, MLP);
  tcast_k<<<dim3(HID/32, MLP/32), dim3(32,8), 0, stream>>>(w_fc2, Wt2, MLP, HID);
  mods_k<<<dim3(27, NB), 256, 0, stream>>>(cvec, w_ada, b_ada, modsb);
  kv_k<<<dim3(9, 16), 256, 0, stream>>>(x, modsb, w1, b1, kb, vb);
  u2_k<<<dim3(HID/16, 16), 256, 0, stream>>>(w2, kb, modsb, ub, A1b);
  sred_k<<<16, 256, 0, stream>>>(ub, A1b, modsb, b2, kb, S0b, S1b);
  p_k<<<MROWS/4, 256, 0, stream>>>(x, A1b, S0b, S1b, pb);
  h_k<<<MROWS/4, 256, 0, stream>>>(pb, vb, modsb, Hb);

  size_t actFull = (size_t)MROWS * MLP * 2;
  int nch = 1;
  while (nch < 8 && O_ACT + actFull/nch > ws_size) nch <<= 1;
  int rowsPer = MROWS / nch;

  for (int chn = 0; chn < nch; chn++){
    int r0 = chn * rowsPer;
    int nTm = rowsPer / 256;
    gemm8_k<0, HID><<<nTm*(MLP/256), 512, 0, stream>>>(
        Hb + (size_t)r0*HID, Wt1, MLP/256, b_fc1,
        actb, nullptr, nullptr, nullptr, nullptr, 0);
    gemm8_k<1, MLP><<<nTm*(NPAD2/256), 512, 0, stream>>>(
        actb, Wt2, NPAD2/256, b_fc2,
        nullptr, out, pb, vb, modsb, r0);
  }
  (void)in_sizes; (void)n_in; (void)out_size;
}